// Round 7
// baseline (235.304 us; speedup 1.0000x reference)
//
#include <hip/hip_runtime.h>
#include <hip/hip_bf16.h>
#include <math.h>

#define NH   4
#define DH   16
#define CH   64
#define KNN  10
#define KS   4
#define NV   4096
#define NB   4
#define MHID 256
#define BN   (NB * NV)

// canonical param-buffer offsets (f32 elements)
#define P_LN1G  0
#define P_LN1B  64
#define P_LN2G  128
#define P_LN2B  192
#define P_WQKV  256
#define P_BQKV  12544
#define P_WPROJ 12736
#define P_BPROJ 16832
#define P_W1    16896
#define P_B1    33280
#define P_W2    33536
#define P_B2    49920
#define P_TOT   49984

typedef __hip_bfloat16 bf16;

__device__ __forceinline__ float b2f(bf16 x) { return __bfloat162float(x); }

__device__ __forceinline__ float cvt(const void* p, int i, int isbf) {
  return isbf ? b2f(((const bf16*)p)[i]) : ((const float*)p)[i];
}

__device__ __forceinline__ float wave_sum_f32(float v) {
#pragma unroll
  for (int m = 32; m >= 1; m >>= 1) v += __shfl_xor(v, m, 64);
  return v;
}

// lexicographic wave-min over (hi, lo) pairs (knn fallback path only)
__device__ __forceinline__ void wave_min_kv(unsigned& hi, unsigned& lo) {
#pragma unroll
  for (int m = 32; m >= 1; m >>= 1) {
    unsigned ohi = __shfl_xor(hi, m, 64);
    unsigned olo = __shfl_xor(lo, m, 64);
    if (ohi < hi || (ohi == hi && olo < lo)) { hi = ohi; lo = olo; }
  }
}

__device__ __forceinline__ float rdlane(float v, int src) {
  return __uint_as_float(__builtin_amdgcn_readlane(__float_as_uint(v), src));
}

__device__ __forceinline__ float tanh_fast(float u) {
  // 1 - 2/(e^{2u}+1); saturates correctly at +/-inf
  float e = __expf(2.0f * u);
  return 1.0f - 2.0f / (e + 1.0f);
}

// identical d2 expression everywhere (exactness anchor)
__device__ __forceinline__ float d2f(float x, float y, float z,
                                     float qx, float qy, float qz) {
  float dx = x - qx, dy = y - qy, dz = z - qz;
  return dx * dx + dy * dy + dz * dz;
}

// ---------------- K0: storage-dtype detection ----------------
__global__ __launch_bounds__(64) void k_detect(
    const unsigned short* __restrict__ x_u16,
    const unsigned* __restrict__ m_u32, int* __restrict__ flags)
{
  const int lane = threadIdx.x;
  int cnt = 0;
#pragma unroll
  for (int k = 0; k < 4; ++k) {
    unsigned short w = x_u16[lane * 4 + k];
    int e = (w >> 7) & 0xFF;
    cnt += (e >= 100 && e <= 140);
  }
#pragma unroll
  for (int m = 32; m >= 1; m >>= 1) cnt += __shfl_xor(cnt, m, 64);
  unsigned big = (m_u32[lane] > 1u) ? 1u : 0u;
#pragma unroll
  for (int m = 32; m >= 1; m >>= 1) big |= __shfl_xor(big, m, 64);
  if (lane == 0) { flags[0] = (cnt >= 205) ? 1 : 0; flags[1] = big ? 1 : 0; }
}

// ---------------- K0b: canonicalize inputs ----------------
__global__ __launch_bounds__(256) void k_ingest(
    const void* xin, const void* coords, const void* maskr,
    const void* ln1g, const void* ln1b, const void* ln2g, const void* ln2b,
    const void* wqkv, const void* bqkv, const void* wproj, const void* bproj,
    const void* w1, const void* b1, const void* w2, const void* b2,
    const int* __restrict__ flags,
    float* __restrict__ xcan, float* __restrict__ ccan,
    float* __restrict__ pcan, int* __restrict__ mcan)
{
  const int isbf = flags[0];
  const int m8 = flags[1];
  int id = blockIdx.x * 256 + threadIdx.x;
  const int n0 = BN * CH, n1 = NB * NV * 3, n2 = P_TOT, n3 = BN;
  if (id < n0) { xcan[id] = cvt(xin, id, isbf); return; }
  id -= n0;
  if (id < n1) { ccan[id] = cvt(coords, id, isbf); return; }
  id -= n1;
  if (id < n2) {
    const void* src; int off;
    if      (id < P_LN1B)  { src = ln1g;  off = id - P_LN1G; }
    else if (id < P_LN2G)  { src = ln1b;  off = id - P_LN1B; }
    else if (id < P_LN2B)  { src = ln2g;  off = id - P_LN2G; }
    else if (id < P_WQKV)  { src = ln2b;  off = id - P_LN2B; }
    else if (id < P_BQKV)  { src = wqkv;  off = id - P_WQKV; }
    else if (id < P_WPROJ) { src = bqkv;  off = id - P_BQKV; }
    else if (id < P_BPROJ) { src = wproj; off = id - P_WPROJ; }
    else if (id < P_W1)    { src = bproj; off = id - P_BPROJ; }
    else if (id < P_B1)    { src = w1;    off = id - P_W1; }
    else if (id < P_W2)    { src = b1;    off = id - P_B1; }
    else if (id < P_B2)    { src = w2;    off = id - P_W2; }
    else                   { src = b2;    off = id - P_B2; }
    pcan[id] = cvt(src, off, isbf);
    return;
  }
  id -= n2;
  if (id < n3) {
    mcan[id] = m8 ? (int)(((const unsigned char*)maskr)[id] != 0)
                  : (int)(((const int*)maskr)[id] != 0);
  }
}

// ---------------- K1: LN1 + QKV (wave-per-4-rows, LDS weights) ----------------
__global__ __launch_bounds__(256) void k_ln_qkv(
    const float* __restrict__ x, const float* __restrict__ pcan,
    float* __restrict__ qkv)
{
  __shared__ float wl[CH * 192];
  __shared__ float bq[192];
  const int tid = threadIdx.x;
  for (int i = tid; i < CH * 192; i += 256) wl[i] = pcan[P_WQKV + i];
  if (tid < 192) bq[tid] = pcan[P_BQKV + tid];
  __syncthreads();
  const int wave = tid >> 6, lane = tid & 63;
  const int row0 = blockIdx.x * 16 + wave * 4;
  const float gg = pcan[P_LN1G + lane], bb = pcan[P_LN1B + lane];

  float xn[4];
#pragma unroll
  for (int r = 0; r < 4; ++r) {
    float v = x[(size_t)(row0 + r) * CH + lane];
    float m = wave_sum_f32(v) * (1.0f / 64.0f);
    float d = v - m;
    float var = wave_sum_f32(d * d) * (1.0f / 64.0f);
    float rs = 1.0f / sqrtf(var + 1e-5f);
    xn[r] = d * rs * gg + bb;
  }

  const int n0 = 3 * lane;
  float a[4][3];
#pragma unroll
  for (int r = 0; r < 4; ++r) {
    a[r][0] = bq[n0]; a[r][1] = bq[n0 + 1]; a[r][2] = bq[n0 + 2];
  }
  for (int c = 0; c < CH; ++c) {
    float w0 = wl[c * 192 + n0];
    float w1 = wl[c * 192 + n0 + 1];
    float w2 = wl[c * 192 + n0 + 2];
#pragma unroll
    for (int r = 0; r < 4; ++r) {
      float s = rdlane(xn[r], c);
      a[r][0] = fmaf(s, w0, a[r][0]);
      a[r][1] = fmaf(s, w1, a[r][1]);
      a[r][2] = fmaf(s, w2, a[r][2]);
    }
  }
#pragma unroll
  for (int r = 0; r < 4; ++r) {
    size_t o = (size_t)(row0 + r) * 192 + n0;
    qkv[o] = a[r][0]; qkv[o + 1] = a[r][1]; qkv[o + 2] = a[r][2];
  }
}

// ---------------- K2: KNN — R5 structure (known-good 58 us) ----------------
#define KROWS 4
#define CAP   128
__global__ __launch_bounds__(256) void k_knn(
    const float* __restrict__ ccan, const int* __restrict__ mcan,
    int* __restrict__ nbr)
{
  __shared__ float4 sx[NV / 4], sy[NV / 4], sz[NV / 4];   // 48 KB SoA
  __shared__ unsigned long long sbuf[KROWS][CAP];         // 4 KB
  const int tid = threadIdx.x;
  const int row0 = blockIdx.x * KROWS;
  const int b = row0 >> 12;
  const float* cb = ccan + (size_t)b * NV * 3;
  const int* mb = mcan + b * NV;

  float* fx = (float*)sx; float* fy = (float*)sy; float* fz = (float*)sz;
  for (int j = tid; j < NV; j += 256) {
    bool v = mb[j] != 0;
    float x = cb[j * 3], y = cb[j * 3 + 1], z = cb[j * 3 + 2];
    fx[j] = v ? x : 1e4f;
    fy[j] = v ? y : 1e4f;
    fz[j] = v ? z : 1e4f;
  }
  __syncthreads();
  const int wave = tid >> 6, lane = tid & 63;
  const int qi = (row0 & (NV - 1)) + wave;
  const float qx = cb[qi * 3], qy = cb[qi * 3 + 1], qz = cb[qi * 3 + 2];

  float bmin = 1e30f;
#pragma unroll 4
  for (int t = 0; t < 16; ++t) {
    float4 X = sx[lane + t * 64], Y = sy[lane + t * 64], Z = sz[lane + t * 64];
    float d0 = d2f(X.x, Y.x, Z.x, qx, qy, qz);
    float d1 = d2f(X.y, Y.y, Z.y, qx, qy, qz);
    float d2 = d2f(X.z, Y.z, Z.z, qx, qy, qz);
    float d3 = d2f(X.w, Y.w, Z.w, qx, qy, qz);
    bmin = fminf(bmin, fminf(fminf(d0, d1), fminf(d2, d3)));
  }

  const unsigned lm = __float_as_uint(bmin);
  unsigned acc = 0;
#pragma unroll 1
  for (int bit = 31; bit >= 0; --bit) {
    unsigned tr = acc | (1u << bit);
    int cnt = __popcll(__ballot(lm < tr));
    if (cnt <= KNN - 1) acc = tr;
  }
  const float T = __uint_as_float(acc + 8);

  int base = 0;
  const unsigned long long below = (lane == 0) ? 0ull : (~0ull >> (64 - lane));
#pragma unroll 4
  for (int t = 0; t < 16; ++t) {
    float4 X = sx[lane + t * 64], Y = sy[lane + t * 64], Z = sz[lane + t * 64];
    float dd[4];
    dd[0] = d2f(X.x, Y.x, Z.x, qx, qy, qz);
    dd[1] = d2f(X.y, Y.y, Z.y, qx, qy, qz);
    dd[2] = d2f(X.z, Y.z, Z.z, qx, qy, qz);
    dd[3] = d2f(X.w, Y.w, Z.w, qx, qy, qz);
#pragma unroll
    for (int e = 0; e < 4; ++e) {
      bool s = (dd[e] <= T);
      unsigned long long bal = __ballot(s);
      if (bal) {
        int pos = base + __popcll(bal & below);
        unsigned j = 4u * (unsigned)(lane + t * 64) + (unsigned)e;
        if (s && pos < CAP)
          sbuf[wave][pos] =
              ((unsigned long long)__float_as_uint(dd[e]) << 32) | j;
        base += __popcll(bal);
      }
    }
  }
  const int c = base;
  const int grow = row0 + wave;

  if (c >= KNN && c <= CAP) {
#pragma unroll
    for (int o = 0; o < 2; ++o) {
      int idx = lane + o * 64;
      if (idx < c) {
        unsigned long long mykey = sbuf[wave][idx];
        int rank = 0;
        for (int i = 0; i < c; ++i) rank += (sbuf[wave][i] < mykey);
        if (rank < KNN)
          nbr[(size_t)grow * KNN + rank] = (int)(mykey & (NV - 1));
      }
    }
  } else {
    unsigned long long arr[KNN];
#pragma unroll
    for (int t = 0; t < KNN; ++t) arr[t] = ~0ull;
    for (int t = 0; t < 16; ++t) {
      float4 X = sx[lane + t * 64], Y = sy[lane + t * 64], Z = sz[lane + t * 64];
      float dd[4];
      dd[0] = d2f(X.x, Y.x, Z.x, qx, qy, qz);
      dd[1] = d2f(X.y, Y.y, Z.y, qx, qy, qz);
      dd[2] = d2f(X.z, Y.z, Z.z, qx, qy, qz);
      dd[3] = d2f(X.w, Y.w, Z.w, qx, qy, qz);
#pragma unroll
      for (int e = 0; e < 4; ++e) {
        unsigned j = 4u * (unsigned)(lane + t * 64) + (unsigned)e;
        unsigned long long key =
            ((unsigned long long)__float_as_uint(dd[e]) << 32) | j;
        if (key < arr[KNN - 1]) {
          arr[KNN - 1] = key;
#pragma unroll
          for (int t2 = KNN - 1; t2 > 0; --t2) {
            unsigned long long a = arr[t2 - 1], cc = arr[t2];
            if (cc < a) { arr[t2 - 1] = cc; arr[t2] = a; }
          }
        }
      }
    }
    unsigned myj = 0;
#pragma unroll 1
    for (int r = 0; r < KNN; ++r) {
      unsigned hi = (unsigned)(arr[0] >> 32);
      unsigned lo = (unsigned)(arr[0] & 0xffffffffu);
      wave_min_kv(hi, lo);
      if (lane == (int)((lo >> 2) & 63u)) {
#pragma unroll
        for (int t = 0; t < KNN - 1; ++t) arr[t] = arr[t + 1];
        arr[KNN - 1] = ~0ull;
      }
      if (lane == r) myj = lo;
    }
    if (lane < KNN) nbr[(size_t)grow * KNN + lane] = (int)(myj & (NV - 1));
  }
}

// ---------------- K3: attention + proj + residual (full-lane rewrite) ----------------
// 16 rows/block, wave per 4 rows. lane = h*16 + d.
__global__ __launch_bounds__(256) void k_attn(
    const float* __restrict__ qkv, const int* __restrict__ nbr,
    const int* __restrict__ mcan, const float* __restrict__ xcan,
    const float* __restrict__ pcan, float* __restrict__ xres)
{
  __shared__ float wp[CH * CH];   // 16 KB wproj [c][n]
  __shared__ float bp[CH];
  const int tid = threadIdx.x;
  for (int i = tid; i < CH * CH; i += 256) wp[i] = pcan[P_WPROJ + i];
  if (tid < CH) bp[tid] = pcan[P_BPROJ + tid];
  __syncthreads();
  const int wave = tid >> 6, lane = tid & 63;
  const int row0 = blockIdx.x * 16 + wave * 4;
  const int b = row0 / NV;          // 16-row blocks never straddle batches

#pragma unroll 1
  for (int r = 0; r < 4; ++r) {
    const int row = row0 + r;
    // neighbor ids + mask penalty live in lanes 0..9
    int jv = 0; float pen = 0.f;
    if (lane < KNN) {
      jv = nbr[(size_t)row * KNN + lane] & (NV - 1);
      pen = mcan[b * NV + jv] ? 0.0f : -1e9f;
    }
    // ---- QK^T: coalesced gathers + 16-lane shuffle-tree reduce ----
    const float qv = qkv[(size_t)row * 192 + lane];
    float sc_mine = -1e30f;
#pragma unroll 1
    for (int kk = 0; kk < KNN; ++kk) {
      int j = __builtin_amdgcn_readlane(jv, kk);
      float kv = qkv[(size_t)(b * NV + j) * 192 + 64 + lane];
      float p = qv * kv;
      p += __shfl_xor(p, 1); p += __shfl_xor(p, 2);
      p += __shfl_xor(p, 4); p += __shfl_xor(p, 8);
      if ((lane & 15) == kk) sc_mine = p;
    }
    float myscore = sc_mine * 0.25f + __shfl(pen, lane & 15);

    // ---- top-4 (max score, tie -> lower index; exact jax tie-break) ----
    float s = myscore; int kidx = lane & 15;
    float sv[KS]; int sk[KS];
#pragma unroll
    for (int t = 0; t < KS; ++t) {
      float cs = s; int ck = kidx;
#pragma unroll
      for (int m = 1; m <= 8; m <<= 1) {
        float os = __shfl_xor(cs, m); int ok = __shfl_xor(ck, m);
        if (os > cs || (os == cs && ok < ck)) { cs = os; ck = ok; }
      }
      sv[t] = cs; sk[t] = ck;
      if ((lane & 15) == ck) s = -INFINITY;
    }
    // ---- softmax over the 4 ----
    float e[KS], sum = 0.f;
#pragma unroll
    for (int t = 0; t < KS; ++t) { e[t] = expf(sv[t] - sv[0]); sum += e[t]; }
    float inv = 1.0f / sum;

    // ---- PV: 4 coalesced gathers ----
    float o = 0.f;
#pragma unroll
    for (int t = 0; t < KS; ++t) {
      int j = __shfl(jv, sk[t]);   // sk[t] uniform per 16-group, varies per head
      o += (e[t] * inv) * qkv[(size_t)(b * NV + j) * 192 + 128 + lane];
    }

    // ---- proj + residual ----
    float acc = bp[lane];
    for (int c = 0; c < CH; ++c)
      acc = fmaf(rdlane(o, c), wp[c * CH + lane], acc);
    float a = mcan[row] ? acc : 0.0f;
    xres[(size_t)row * CH + lane] = 0.5f * a + xcan[(size_t)row * CH + lane];
  }
}

// ---------------- K4: LN2 + MLP + residual (vectorized LDS, fast tanh) ----------------
#define W2S (MHID + 4)   // padded w2t row stride (ushorts)
__global__ __launch_bounds__(256) void k_mlp(
    const float* __restrict__ xres, const float* __restrict__ pcan,
    const int* __restrict__ flags, void* __restrict__ out)
{
  __shared__ unsigned short w1b[CH * MHID];   // [c][n] 32 KB bf16
  __shared__ unsigned short w2t[CH * W2S];    // [c][h] padded 33.3 KB bf16
  __shared__ float b1f[MHID];
  __shared__ float b2f_[CH];
  const int tid = threadIdx.x;
  for (int i = tid; i < CH * MHID; i += 256) {
    w1b[i] = __bfloat16_as_ushort(__float2bfloat16(pcan[P_W1 + i]));
    int h = i >> 6, c = i & 63;               // i = h*CH + c (coalesced read)
    w2t[c * W2S + h] = __bfloat16_as_ushort(__float2bfloat16(pcan[P_W2 + i]));
  }
  if (tid < MHID) b1f[tid] = pcan[P_B1 + tid];
  if (tid < CH)   b2f_[tid] = pcan[P_B2 + tid];
  __syncthreads();
  const int wave = tid >> 6, lane = tid & 63;
  const int row0 = blockIdx.x * 16 + wave * 4;
  const float gg = pcan[P_LN2G + lane], bb = pcan[P_LN2B + lane];

  float xn[4], xv[4];
#pragma unroll
  for (int r = 0; r < 4; ++r) {
    float v = xres[(size_t)(row0 + r) * CH + lane];
    xv[r] = v;
    float m = wave_sum_f32(v) * (1.0f / 64.0f);
    float d = v - m;
    float var = wave_sum_f32(d * d) * (1.0f / 64.0f);
    float rs = 1.0f / sqrtf(var + 1e-5f);
    xn[r] = d * rs * gg + bb;
  }

  // fc1: cols n = 4*lane + i, ushort4 weight reads
  const int n0 = 4 * lane;
  float g[4][4];
#pragma unroll
  for (int r = 0; r < 4; ++r)
#pragma unroll
    for (int i = 0; i < 4; ++i) g[r][i] = b1f[n0 + i];
  for (int c = 0; c < CH; ++c) {
    ushort4 w4 = *(const ushort4*)&w1b[c * MHID + n0];
    float w0 = b2f(__ushort_as_bfloat16(w4.x));
    float w1 = b2f(__ushort_as_bfloat16(w4.y));
    float w2 = b2f(__ushort_as_bfloat16(w4.z));
    float w3 = b2f(__ushort_as_bfloat16(w4.w));
#pragma unroll
    for (int r = 0; r < 4; ++r) {
      float s = rdlane(xn[r], c);
      g[r][0] = fmaf(s, w0, g[r][0]);
      g[r][1] = fmaf(s, w1, g[r][1]);
      g[r][2] = fmaf(s, w2, g[r][2]);
      g[r][3] = fmaf(s, w3, g[r][3]);
    }
  }
  // gelu (tanh approx, fast tanh via exp)
#pragma unroll
  for (int r = 0; r < 4; ++r)
#pragma unroll
    for (int i = 0; i < 4; ++i) {
      float t = g[r][i];
      float u = 0.7978845608028654f * (t + 0.044715f * t * t * t);
      g[r][i] = 0.5f * t * (1.0f + tanh_fast(u));
    }

  // fc2: out col = lane; hidden h = hb*4 + i held at lane hb, reg i
  float acc2[4];
#pragma unroll
  for (int r = 0; r < 4; ++r) acc2[r] = b2f_[lane];
  for (int hb = 0; hb < MHID / 4; ++hb) {
    ushort4 w4 = *(const ushort4*)&w2t[lane * W2S + 4 * hb];
    float wv[4];
    wv[0] = b2f(__ushort_as_bfloat16(w4.x));
    wv[1] = b2f(__ushort_as_bfloat16(w4.y));
    wv[2] = b2f(__ushort_as_bfloat16(w4.z));
    wv[3] = b2f(__ushort_as_bfloat16(w4.w));
#pragma unroll
    for (int i = 0; i < 4; ++i)
#pragma unroll
      for (int r = 0; r < 4; ++r)
        acc2[r] = fmaf(rdlane(g[r][i], hb), wv[i], acc2[r]);
  }
#pragma unroll
  for (int r = 0; r < 4; ++r) {
    float o = 0.5f * acc2[r] + xv[r];
    size_t idx = (size_t)(row0 + r) * CH + lane;
    if (flags[0]) ((bf16*)out)[idx] = __float2bfloat16(o);
    else          ((float*)out)[idx] = o;
  }
}

extern "C" void kernel_launch(void* const* d_in, const int* in_sizes, int n_in,
                              void* d_out, int out_size, void* d_ws, size_t ws_size,
                              hipStream_t stream)
{
  char* ws = (char*)d_ws;
  float* qkv  = (float*)(ws);
  float* xres = (float*)(ws + 12582912);
  float* xcan = (float*)(ws + 16777216);
  float* ccan = (float*)(ws + 20971520);
  float* pcan = (float*)(ws + 21168128);
  int*   mcan = (int*)  (ws + 21368064);
  int*   nbr  = (int*)  (ws + 21433600);
  int*   flags= (int*)  (ws + 22088960);

  k_detect<<<1, 64, 0, stream>>>((const unsigned short*)d_in[0],
                                 (const unsigned*)d_in[2], flags);
  const int total = BN * CH + NB * NV * 3 + P_TOT + BN;
  k_ingest<<<(total + 255) / 256, 256, 0, stream>>>(
      d_in[0], d_in[1], d_in[2], d_in[3], d_in[4], d_in[5], d_in[6],
      d_in[7], d_in[8], d_in[9], d_in[10], d_in[11], d_in[12], d_in[13], d_in[14],
      flags, xcan, ccan, pcan, mcan);
  k_ln_qkv<<<BN / 16, 256, 0, stream>>>(xcan, pcan, qkv);
  k_knn<<<BN / KROWS, 256, 0, stream>>>(ccan, mcan, nbr);
  k_attn<<<BN / 16, 256, 0, stream>>>(qkv, nbr, mcan, xcan, pcan, xres);
  k_mlp<<<BN / 16, 256, 0, stream>>>(xres, pcan, flags, d_out);
}

// Round 8
// 229.263 us; speedup vs baseline: 1.0263x; 1.0263x over previous
//
#include <hip/hip_runtime.h>
#include <hip/hip_bf16.h>
#include <math.h>

#define NH   4
#define DH   16
#define CH   64
#define KNN  10
#define KS   4
#define NV   4096
#define NB   4
#define MHID 256
#define BN   (NB * NV)

// canonical param-buffer offsets (f32 elements)
#define P_LN1G  0
#define P_LN1B  64
#define P_LN2G  128
#define P_LN2B  192
#define P_WQKV  256
#define P_BQKV  12544
#define P_WPROJ 12736
#define P_BPROJ 16832
#define P_W1    16896
#define P_B1    33280
#define P_W2    33536
#define P_B2    49920
#define P_TOT   49984

typedef __hip_bfloat16 bf16;

__device__ __forceinline__ float b2f(bf16 x) { return __bfloat162float(x); }

__device__ __forceinline__ float cvt(const void* p, int i, int isbf) {
  return isbf ? b2f(((const bf16*)p)[i]) : ((const float*)p)[i];
}

__device__ __forceinline__ float wave_sum_f32(float v) {
#pragma unroll
  for (int m = 32; m >= 1; m >>= 1) v += __shfl_xor(v, m, 64);
  return v;
}

// lexicographic wave-min over (hi, lo) pairs (knn fallback path only)
__device__ __forceinline__ void wave_min_kv(unsigned& hi, unsigned& lo) {
#pragma unroll
  for (int m = 32; m >= 1; m >>= 1) {
    unsigned ohi = __shfl_xor(hi, m, 64);
    unsigned olo = __shfl_xor(lo, m, 64);
    if (ohi < hi || (ohi == hi && olo < lo)) { hi = ohi; lo = olo; }
  }
}

__device__ __forceinline__ float rdlane(float v, int src) {
  return __uint_as_float(__builtin_amdgcn_readlane(__float_as_uint(v), src));
}

__device__ __forceinline__ float tanh_fast(float u) {
  float e = __expf(2.0f * u);
  return 1.0f - 2.0f / (e + 1.0f);
}

// identical d2 expression everywhere (exactness anchor)
__device__ __forceinline__ float d2f(float x, float y, float z,
                                     float qx, float qy, float qz) {
  float dx = x - qx, dy = y - qy, dz = z - qz;
  return dx * dx + dy * dy + dz * dz;
}

// ---------------- K0: storage-dtype detection ----------------
__global__ __launch_bounds__(64) void k_detect(
    const unsigned short* __restrict__ x_u16,
    const unsigned* __restrict__ m_u32, int* __restrict__ flags)
{
  const int lane = threadIdx.x;
  int cnt = 0;
#pragma unroll
  for (int k = 0; k < 4; ++k) {
    unsigned short w = x_u16[lane * 4 + k];
    int e = (w >> 7) & 0xFF;
    cnt += (e >= 100 && e <= 140);
  }
#pragma unroll
  for (int m = 32; m >= 1; m >>= 1) cnt += __shfl_xor(cnt, m, 64);
  unsigned big = (m_u32[lane] > 1u) ? 1u : 0u;
#pragma unroll
  for (int m = 32; m >= 1; m >>= 1) big |= __shfl_xor(big, m, 64);
  if (lane == 0) { flags[0] = (cnt >= 205) ? 1 : 0; flags[1] = big ? 1 : 0; }
}

// ---------------- K0b: canonicalize inputs ----------------
__global__ __launch_bounds__(256) void k_ingest(
    const void* xin, const void* coords, const void* maskr,
    const void* ln1g, const void* ln1b, const void* ln2g, const void* ln2b,
    const void* wqkv, const void* bqkv, const void* wproj, const void* bproj,
    const void* w1, const void* b1, const void* w2, const void* b2,
    const int* __restrict__ flags,
    float* __restrict__ xcan, float* __restrict__ ccan,
    float* __restrict__ pcan, int* __restrict__ mcan)
{
  const int isbf = flags[0];
  const int m8 = flags[1];
  int id = blockIdx.x * 256 + threadIdx.x;
  const int n0 = BN * CH, n1 = NB * NV * 3, n2 = P_TOT, n3 = BN;
  if (id < n0) { xcan[id] = cvt(xin, id, isbf); return; }
  id -= n0;
  if (id < n1) { ccan[id] = cvt(coords, id, isbf); return; }
  id -= n1;
  if (id < n2) {
    const void* src; int off;
    if      (id < P_LN1B)  { src = ln1g;  off = id - P_LN1G; }
    else if (id < P_LN2G)  { src = ln1b;  off = id - P_LN1B; }
    else if (id < P_LN2B)  { src = ln2g;  off = id - P_LN2G; }
    else if (id < P_WQKV)  { src = ln2b;  off = id - P_LN2B; }
    else if (id < P_BQKV)  { src = wqkv;  off = id - P_WQKV; }
    else if (id < P_WPROJ) { src = bqkv;  off = id - P_BQKV; }
    else if (id < P_BPROJ) { src = wproj; off = id - P_WPROJ; }
    else if (id < P_W1)    { src = bproj; off = id - P_BPROJ; }
    else if (id < P_B1)    { src = w1;    off = id - P_W1; }
    else if (id < P_W2)    { src = b1;    off = id - P_B1; }
    else if (id < P_B2)    { src = w2;    off = id - P_W2; }
    else                   { src = b2;    off = id - P_B2; }
    pcan[id] = cvt(src, off, isbf);
    return;
  }
  id -= n2;
  if (id < n3) {
    mcan[id] = m8 ? (int)(((const unsigned char*)maskr)[id] != 0)
                  : (int)(((const int*)maskr)[id] != 0);
  }
}

// ---------------- K1: LN1 + QKV (wave-per-4-rows, LDS weights) ----------------
__global__ __launch_bounds__(256) void k_ln_qkv(
    const float* __restrict__ x, const float* __restrict__ pcan,
    float* __restrict__ qkv)
{
  __shared__ float wl[CH * 192];
  __shared__ float bq[192];
  const int tid = threadIdx.x;
  for (int i = tid; i < CH * 192; i += 256) wl[i] = pcan[P_WQKV + i];
  if (tid < 192) bq[tid] = pcan[P_BQKV + tid];
  __syncthreads();
  const int wave = tid >> 6, lane = tid & 63;
  const int row0 = blockIdx.x * 16 + wave * 4;
  const float gg = pcan[P_LN1G + lane], bb = pcan[P_LN1B + lane];

  float xn[4];
#pragma unroll
  for (int r = 0; r < 4; ++r) {
    float v = x[(size_t)(row0 + r) * CH + lane];
    float m = wave_sum_f32(v) * (1.0f / 64.0f);
    float d = v - m;
    float var = wave_sum_f32(d * d) * (1.0f / 64.0f);
    float rs = 1.0f / sqrtf(var + 1e-5f);
    xn[r] = d * rs * gg + bb;
  }

  const int n0 = 3 * lane;
  float a[4][3];
#pragma unroll
  for (int r = 0; r < 4; ++r) {
    a[r][0] = bq[n0]; a[r][1] = bq[n0 + 1]; a[r][2] = bq[n0 + 2];
  }
  for (int c = 0; c < CH; ++c) {
    float w0 = wl[c * 192 + n0];
    float w1 = wl[c * 192 + n0 + 1];
    float w2 = wl[c * 192 + n0 + 2];
#pragma unroll
    for (int r = 0; r < 4; ++r) {
      float s = rdlane(xn[r], c);
      a[r][0] = fmaf(s, w0, a[r][0]);
      a[r][1] = fmaf(s, w1, a[r][1]);
      a[r][2] = fmaf(s, w2, a[r][2]);
    }
  }
#pragma unroll
  for (int r = 0; r < 4; ++r) {
    size_t o = (size_t)(row0 + r) * 192 + n0;
    qkv[o] = a[r][0]; qkv[o + 1] = a[r][1]; qkv[o + 2] = a[r][2];
  }
}

// ---------------- K2: KNN — 2 queries/wave (QW=2), R5 skeleton ----------------
#define QB   8      // queries (rows) per block: 4 waves x 2
#define CAP  64
__global__ __launch_bounds__(256) void k_knn(
    const float* __restrict__ ccan, const int* __restrict__ mcan,
    int* __restrict__ nbr)
{
  __shared__ float4 sx[NV / 4], sy[NV / 4], sz[NV / 4];   // 48 KB SoA
  __shared__ unsigned long long sbuf[QB][CAP];            // 4 KB
  const int tid = threadIdx.x;
  const int row0 = blockIdx.x * QB;
  const int b = row0 >> 12;
  const float* cb = ccan + (size_t)b * NV * 3;
  const int* mb = mcan + b * NV;

  // stage coords SoA, mask folded (invalid -> 1e4 => d2~3e8 >> 768 max real)
  float* fx = (float*)sx; float* fy = (float*)sy; float* fz = (float*)sz;
  for (int j = tid; j < NV; j += 256) {
    bool v = mb[j] != 0;
    float x = cb[j * 3], y = cb[j * 3 + 1], z = cb[j * 3 + 2];
    fx[j] = v ? x : 1e4f;
    fy[j] = v ? y : 1e4f;
    fz[j] = v ? z : 1e4f;
  }
  __syncthreads();
  const int wave = tid >> 6, lane = tid & 63;
  const int qA = (row0 & (NV - 1)) + wave * 2;
  const int qB = qA + 1;
  // query coords RAW from global (row's own mask doesn't apply to the query)
  const float axq = cb[qA * 3], ayq = cb[qA * 3 + 1], azq = cb[qA * 3 + 2];
  const float bxq = cb[qB * 3], byq = cb[qB * 3 + 1], bzq = cb[qB * 3 + 2];

  // ---- pass 1: per-lane min d2 for both queries ----
  float bminA = 1e30f, bminB = 1e30f;
#pragma unroll 4
  for (int t = 0; t < 16; ++t) {
    float4 X = sx[lane + t * 64], Y = sy[lane + t * 64], Z = sz[lane + t * 64];
    float a0 = d2f(X.x, Y.x, Z.x, axq, ayq, azq);
    float a1 = d2f(X.y, Y.y, Z.y, axq, ayq, azq);
    float a2 = d2f(X.z, Y.z, Z.z, axq, ayq, azq);
    float a3 = d2f(X.w, Y.w, Z.w, axq, ayq, azq);
    bminA = fminf(bminA, fminf(fminf(a0, a1), fminf(a2, a3)));
    float b0 = d2f(X.x, Y.x, Z.x, bxq, byq, bzq);
    float b1 = d2f(X.y, Y.y, Z.y, bxq, byq, bzq);
    float b2 = d2f(X.z, Y.z, Z.z, bxq, byq, bzq);
    float b3 = d2f(X.w, Y.w, Z.w, bxq, byq, bzq);
    bminB = fminf(bminB, fminf(fminf(b0, b1), fminf(b2, b3)));
  }

  // ---- thresholds via ballot binary search (10th-smallest lane-min) ----
  float TA, TB;
  {
    unsigned lm = __float_as_uint(bminA), acc = 0;
#pragma unroll 1
    for (int bit = 31; bit >= 0; --bit) {
      unsigned tr = acc | (1u << bit);
      if (__popcll(__ballot(lm < tr)) <= KNN - 1) acc = tr;
    }
    TA = __uint_as_float(acc + 8);
  }
  {
    unsigned lm = __float_as_uint(bminB), acc = 0;
#pragma unroll 1
    for (int bit = 31; bit >= 0; --bit) {
      unsigned tr = acc | (1u << bit);
      if (__popcll(__ballot(lm < tr)) <= KNN - 1) acc = tr;
    }
    TB = __uint_as_float(acc + 8);
  }

  // ---- pass 2: ballot-compact survivors per query ----
  int baseA = 0, baseB = 0;
  const unsigned long long below = (lane == 0) ? 0ull : (~0ull >> (64 - lane));
#pragma unroll 2
  for (int t = 0; t < 16; ++t) {
    float4 X = sx[lane + t * 64], Y = sy[lane + t * 64], Z = sz[lane + t * 64];
    float ex[4] = {X.x, X.y, X.z, X.w};
    float ey[4] = {Y.x, Y.y, Y.z, Y.w};
    float ez[4] = {Z.x, Z.y, Z.z, Z.w};
#pragma unroll
    for (int e = 0; e < 4; ++e) {
      unsigned j = 4u * (unsigned)(lane + t * 64) + (unsigned)e;
      float dA = d2f(ex[e], ey[e], ez[e], axq, ayq, azq);
      float dB = d2f(ex[e], ey[e], ez[e], bxq, byq, bzq);
      {
        bool s = (dA <= TA);
        unsigned long long bal = __ballot(s);
        if (bal) {
          int pos = baseA + __popcll(bal & below);
          if (s && pos < CAP)
            sbuf[wave * 2][pos] =
                ((unsigned long long)__float_as_uint(dA) << 32) | j;
          baseA += __popcll(bal);
        }
      }
      {
        bool s = (dB <= TB);
        unsigned long long bal = __ballot(s);
        if (bal) {
          int pos = baseB + __popcll(bal & below);
          if (s && pos < CAP)
            sbuf[wave * 2 + 1][pos] =
                ((unsigned long long)__float_as_uint(dB) << 32) | j;
          baseB += __popcll(bal);
        }
      }
    }
  }

  // ---- exact rank-by-count selection per query ----
#pragma unroll 1
  for (int qq = 0; qq < 2; ++qq) {
    const int c = (qq == 0) ? baseA : baseB;
    const int slot = wave * 2 + qq;
    const int grow = row0 + wave * 2 + qq;
    const float qx = (qq == 0) ? axq : bxq;
    const float qy = (qq == 0) ? ayq : byq;
    const float qz = (qq == 0) ? azq : bzq;
    if (c <= CAP) {          // c >= 10 guaranteed (10 lane-mins <= T)
      if (lane < c) {
        unsigned long long mykey = sbuf[slot][lane];
        int rank = 0;
        for (int i = 0; i < c; ++i) rank += (sbuf[slot][i] < mykey);
        if (rank < KNN)
          nbr[(size_t)grow * KNN + rank] = (int)(mykey & (NV - 1));
      }
    } else {
      // ---- exact fallback (overflow — effectively unreachable) ----
      unsigned long long arr[KNN];
#pragma unroll
      for (int t = 0; t < KNN; ++t) arr[t] = ~0ull;
      for (int t = 0; t < 16; ++t) {
        float4 X = sx[lane + t * 64], Y = sy[lane + t * 64], Z = sz[lane + t * 64];
        float dd[4];
        dd[0] = d2f(X.x, Y.x, Z.x, qx, qy, qz);
        dd[1] = d2f(X.y, Y.y, Z.y, qx, qy, qz);
        dd[2] = d2f(X.z, Y.z, Z.z, qx, qy, qz);
        dd[3] = d2f(X.w, Y.w, Z.w, qx, qy, qz);
#pragma unroll
        for (int e = 0; e < 4; ++e) {
          unsigned j = 4u * (unsigned)(lane + t * 64) + (unsigned)e;
          unsigned long long key =
              ((unsigned long long)__float_as_uint(dd[e]) << 32) | j;
          if (key < arr[KNN - 1]) {
            arr[KNN - 1] = key;
#pragma unroll
            for (int t2 = KNN - 1; t2 > 0; --t2) {
              unsigned long long a = arr[t2 - 1], cc = arr[t2];
              if (cc < a) { arr[t2 - 1] = cc; arr[t2] = a; }
            }
          }
        }
      }
      unsigned myj = 0;
#pragma unroll 1
      for (int r = 0; r < KNN; ++r) {
        unsigned hi = (unsigned)(arr[0] >> 32);
        unsigned lo = (unsigned)(arr[0] & 0xffffffffu);
        wave_min_kv(hi, lo);
        if (lane == (int)((lo >> 2) & 63u)) {
#pragma unroll
          for (int t = 0; t < KNN - 1; ++t) arr[t] = arr[t + 1];
          arr[KNN - 1] = ~0ull;
        }
        if (lane == r) myj = lo;
      }
      if (lane < KNN) nbr[(size_t)grow * KNN + lane] = (int)(myj & (NV - 1));
    }
  }
}

// ---------------- K3: attention + proj + residual (R5 version, verbatim) ----------------
#define AROWS 4
__global__ __launch_bounds__(256) void k_attn(
    const float* __restrict__ qkv, const int* __restrict__ nbr,
    const int* __restrict__ mcan, const float* __restrict__ xcan,
    const float* __restrict__ pcan, float* __restrict__ xres)
{
  __shared__ float sc[AROWS][NH][KNN];
  __shared__ float wsel[AROWS][NH][KS];
  __shared__ int   isel[AROWS][NH][KS];
  __shared__ float obuf[AROWS][CH];
  __shared__ int   nb[AROWS][KNN];
  __shared__ float npen[AROWS][KNN];
  const int tid = threadIdx.x;
  const int wave = tid >> 6, lane = tid & 63;
  const int row = blockIdx.x * AROWS + wave;
  const int b = row / NV;

  if (lane < KNN) {
    int j = nbr[(size_t)row * KNN + lane] & (NV - 1);
    nb[wave][lane] = j;
    npen[wave][lane] = mcan[b * NV + j] ? 0.0f : -1e9f;
  }
  __syncthreads();

  if (lane < NH * KNN) {
    int h = lane / KNN, kk = lane % KNN;
    int j = nb[wave][kk];
    const float* qp = qkv + (size_t)row * 192 + h * DH;
    const float* kp = qkv + ((size_t)(b * NV + j)) * 192 + 64 + h * DH;
    float acc = 0.f;
#pragma unroll
    for (int d = 0; d < DH; ++d) acc += qp[d] * kp[d];
    sc[wave][h][kk] = acc * 0.25f + npen[wave][kk];
  }
  __syncthreads();

  if (lane < NH) {
    int h = lane;
    float sv[KS]; int sj[KS];
    unsigned used = 0;
#pragma unroll
    for (int r = 0; r < KS; ++r) {
      float best = -INFINITY; int bi = 0;
#pragma unroll
      for (int kk = 0; kk < KNN; ++kk) {
        float s = sc[wave][h][kk];
        if (!(used & (1u << kk)) && s > best) { best = s; bi = kk; }
      }
      used |= 1u << bi; sv[r] = best; sj[r] = bi;
    }
    float mx = sv[0];
    float e[KS], sum = 0.f;
#pragma unroll
    for (int r = 0; r < KS; ++r) { e[r] = expf(sv[r] - mx); sum += e[r]; }
    float inv = 1.0f / sum;
#pragma unroll
    for (int r = 0; r < KS; ++r) {
      wsel[wave][h][r] = e[r] * inv;
      isel[wave][h][r] = nb[wave][sj[r]];
    }
  }
  __syncthreads();

  {
    int h = lane >> 4, d = lane & 15;
    float o = 0.f;
#pragma unroll
    for (int r = 0; r < KS; ++r) {
      int j = isel[wave][h][r];
      o += wsel[wave][h][r] * qkv[((size_t)(b * NV + j)) * 192 + 128 + h * DH + d];
    }
    obuf[wave][lane] = o;
  }
  __syncthreads();

  {
    float acc = pcan[P_BPROJ + lane];
#pragma unroll 4
    for (int cc = 0; cc < CH; ++cc) acc += obuf[wave][cc] * pcan[P_WPROJ + cc * CH + lane];
    float a = mcan[row] ? acc : 0.0f;
    xres[(size_t)row * CH + lane] = 0.5f * a + xcan[(size_t)row * CH + lane];
  }
}

// ---------------- K4: LN2 + MLP + residual (conflict-free w2, ushort4 w1) ----------------
__global__ __launch_bounds__(256) void k_mlp(
    const float* __restrict__ xres, const float* __restrict__ pcan,
    const int* __restrict__ flags, void* __restrict__ out)
{
  __shared__ unsigned short w1b[CH * MHID];   // [c][n] 32 KB bf16
  __shared__ unsigned short w2b[MHID * CH];   // [h][c] 32 KB bf16 (conflict-free)
  __shared__ float b1f[MHID];
  __shared__ float b2f_[CH];
  const int tid = threadIdx.x;
  for (int i = tid; i < CH * MHID; i += 256) {
    w1b[i] = __bfloat16_as_ushort(__float2bfloat16(pcan[P_W1 + i]));
    w2b[i] = __bfloat16_as_ushort(__float2bfloat16(pcan[P_W2 + i]));
  }
  if (tid < MHID) b1f[tid] = pcan[P_B1 + tid];
  if (tid < CH)   b2f_[tid] = pcan[P_B2 + tid];
  __syncthreads();
  const int wave = tid >> 6, lane = tid & 63;
  const int row0 = blockIdx.x * 16 + wave * 4;
  const float gg = pcan[P_LN2G + lane], bb = pcan[P_LN2B + lane];

  float xn[4], xv[4];
#pragma unroll
  for (int r = 0; r < 4; ++r) {
    float v = xres[(size_t)(row0 + r) * CH + lane];
    xv[r] = v;
    float m = wave_sum_f32(v) * (1.0f / 64.0f);
    float d = v - m;
    float var = wave_sum_f32(d * d) * (1.0f / 64.0f);
    float rs = 1.0f / sqrtf(var + 1e-5f);
    xn[r] = d * rs * gg + bb;
  }

  // fc1: cols n = 4*lane + i, ushort4 weight reads (2-way bank alias = free)
  const int n0 = 4 * lane;
  float g[4][4];
#pragma unroll
  for (int r = 0; r < 4; ++r)
#pragma unroll
    for (int i = 0; i < 4; ++i) g[r][i] = b1f[n0 + i];
  for (int c = 0; c < CH; ++c) {
    ushort4 w4 = *(const ushort4*)&w1b[c * MHID + n0];
    float w0 = b2f(__ushort_as_bfloat16(w4.x));
    float w1 = b2f(__ushort_as_bfloat16(w4.y));
    float w2 = b2f(__ushort_as_bfloat16(w4.z));
    float w3 = b2f(__ushort_as_bfloat16(w4.w));
#pragma unroll
    for (int r = 0; r < 4; ++r) {
      float s = rdlane(xn[r], c);
      g[r][0] = fmaf(s, w0, g[r][0]);
      g[r][1] = fmaf(s, w1, g[r][1]);
      g[r][2] = fmaf(s, w2, g[r][2]);
      g[r][3] = fmaf(s, w3, g[r][3]);
    }
  }
  // gelu (tanh approx, fast tanh via exp)
#pragma unroll
  for (int r = 0; r < 4; ++r)
#pragma unroll
    for (int i = 0; i < 4; ++i) {
      float t = g[r][i];
      float u = 0.7978845608028654f * (t + 0.044715f * t * t * t);
      g[r][i] = 0.5f * t * (1.0f + tanh_fast(u));
    }

  // fc2: out col = lane; hidden h = hb*4 + i held at lane hb, reg i
  float acc2[4];
#pragma unroll
  for (int r = 0; r < 4; ++r) acc2[r] = b2f_[lane];
  for (int hb = 0; hb < MHID / 4; ++hb) {
#pragma unroll
    for (int i = 0; i < 4; ++i) {
      int h = hb * 4 + i;
      float wv = b2f(__ushort_as_bfloat16(w2b[h * CH + lane]));
#pragma unroll
      for (int r = 0; r < 4; ++r)
        acc2[r] = fmaf(rdlane(g[r][i], hb), wv, acc2[r]);
    }
  }
#pragma unroll
  for (int r = 0; r < 4; ++r) {
    float o = 0.5f * acc2[r] + xv[r];
    size_t idx = (size_t)(row0 + r) * CH + lane;
    if (flags[0]) ((bf16*)out)[idx] = __float2bfloat16(o);
    else          ((float*)out)[idx] = o;
  }
}

extern "C" void kernel_launch(void* const* d_in, const int* in_sizes, int n_in,
                              void* d_out, int out_size, void* d_ws, size_t ws_size,
                              hipStream_t stream)
{
  char* ws = (char*)d_ws;
  float* qkv  = (float*)(ws);
  float* xres = (float*)(ws + 12582912);
  float* xcan = (float*)(ws + 16777216);
  float* ccan = (float*)(ws + 20971520);
  float* pcan = (float*)(ws + 21168128);
  int*   mcan = (int*)  (ws + 21368064);
  int*   nbr  = (int*)  (ws + 21433600);
  int*   flags= (int*)  (ws + 22088960);

  k_detect<<<1, 64, 0, stream>>>((const unsigned short*)d_in[0],
                                 (const unsigned*)d_in[2], flags);
  const int total = BN * CH + NB * NV * 3 + P_TOT + BN;
  k_ingest<<<(total + 255) / 256, 256, 0, stream>>>(
      d_in[0], d_in[1], d_in[2], d_in[3], d_in[4], d_in[5], d_in[6],
      d_in[7], d_in[8], d_in[9], d_in[10], d_in[11], d_in[12], d_in[13], d_in[14],
      flags, xcan, ccan, pcan, mcan);
  k_ln_qkv<<<BN / 16, 256, 0, stream>>>(xcan, pcan, qkv);
  k_knn<<<BN / QB, 256, 0, stream>>>(ccan, mcan, nbr);
  k_attn<<<BN / AROWS, 256, 0, stream>>>(qkv, nbr, mcan, xcan, pcan, xres);
  k_mlp<<<BN / 16, 256, 0, stream>>>(xres, pcan, flags, d_out);
}

// Round 9
// 216.361 us; speedup vs baseline: 1.0875x; 1.0596x over previous
//
#include <hip/hip_runtime.h>
#include <hip/hip_bf16.h>
#include <math.h>

#define NH   4
#define DH   16
#define CH   64
#define KNN  10
#define KS   4
#define NV   4096
#define NB   4
#define MHID 256
#define BN   (NB * NV)

// canonical param-buffer offsets (f32 elements)
#define P_LN1G  0
#define P_LN1B  64
#define P_LN2G  128
#define P_LN2B  192
#define P_WQKV  256
#define P_BQKV  12544
#define P_WPROJ 12736
#define P_BPROJ 16832
#define P_W1    16896
#define P_B1    33280
#define P_W2    33536
#define P_B2    49920
#define P_TOT   49984

typedef __hip_bfloat16 bf16;

__device__ __forceinline__ float b2f(bf16 x) { return __bfloat162float(x); }

__device__ __forceinline__ float cvt(const void* p, int i, int isbf) {
  return isbf ? b2f(((const bf16*)p)[i]) : ((const float*)p)[i];
}

__device__ __forceinline__ float wave_sum_f32(float v) {
#pragma unroll
  for (int m = 32; m >= 1; m >>= 1) v += __shfl_xor(v, m, 64);
  return v;
}

// lexicographic wave-min over (hi, lo) pairs (knn fallback path only)
__device__ __forceinline__ void wave_min_kv(unsigned& hi, unsigned& lo) {
#pragma unroll
  for (int m = 32; m >= 1; m >>= 1) {
    unsigned ohi = __shfl_xor(hi, m, 64);
    unsigned olo = __shfl_xor(lo, m, 64);
    if (ohi < hi || (ohi == hi && olo < lo)) { hi = ohi; lo = olo; }
  }
}

__device__ __forceinline__ float rdlane(float v, int src) {
  return __uint_as_float(__builtin_amdgcn_readlane(__float_as_uint(v), src));
}

__device__ __forceinline__ float tanh_fast(float u) {
  float e = __expf(2.0f * u);
  return 1.0f - 2.0f / (e + 1.0f);
}

// identical d2 expression everywhere (exactness anchor)
__device__ __forceinline__ float d2f(float x, float y, float z,
                                     float qx, float qy, float qz) {
  float dx = x - qx, dy = y - qy, dz = z - qz;
  return dx * dx + dy * dy + dz * dz;
}

// ---------------- K0: storage-dtype detection ----------------
__global__ __launch_bounds__(64) void k_detect(
    const unsigned short* __restrict__ x_u16,
    const unsigned* __restrict__ m_u32, int* __restrict__ flags)
{
  const int lane = threadIdx.x;
  int cnt = 0;
#pragma unroll
  for (int k = 0; k < 4; ++k) {
    unsigned short w = x_u16[lane * 4 + k];
    int e = (w >> 7) & 0xFF;
    cnt += (e >= 100 && e <= 140);
  }
#pragma unroll
  for (int m = 32; m >= 1; m >>= 1) cnt += __shfl_xor(cnt, m, 64);
  unsigned big = (m_u32[lane] > 1u) ? 1u : 0u;
#pragma unroll
  for (int m = 32; m >= 1; m >>= 1) big |= __shfl_xor(big, m, 64);
  if (lane == 0) { flags[0] = (cnt >= 205) ? 1 : 0; flags[1] = big ? 1 : 0; }
}

// ---------------- K0b: canonicalize inputs ----------------
__global__ __launch_bounds__(256) void k_ingest(
    const void* xin, const void* coords, const void* maskr,
    const void* ln1g, const void* ln1b, const void* ln2g, const void* ln2b,
    const void* wqkv, const void* bqkv, const void* wproj, const void* bproj,
    const void* w1, const void* b1, const void* w2, const void* b2,
    const int* __restrict__ flags,
    float* __restrict__ xcan, float* __restrict__ ccan,
    float* __restrict__ pcan, int* __restrict__ mcan)
{
  const int isbf = flags[0];
  const int m8 = flags[1];
  int id = blockIdx.x * 256 + threadIdx.x;
  const int n0 = BN * CH, n1 = NB * NV * 3, n2 = P_TOT, n3 = BN;
  if (id < n0) { xcan[id] = cvt(xin, id, isbf); return; }
  id -= n0;
  if (id < n1) { ccan[id] = cvt(coords, id, isbf); return; }
  id -= n1;
  if (id < n2) {
    const void* src; int off;
    if      (id < P_LN1B)  { src = ln1g;  off = id - P_LN1G; }
    else if (id < P_LN2G)  { src = ln1b;  off = id - P_LN1B; }
    else if (id < P_LN2B)  { src = ln2g;  off = id - P_LN2G; }
    else if (id < P_WQKV)  { src = ln2b;  off = id - P_LN2B; }
    else if (id < P_BQKV)  { src = wqkv;  off = id - P_WQKV; }
    else if (id < P_WPROJ) { src = bqkv;  off = id - P_BQKV; }
    else if (id < P_BPROJ) { src = wproj; off = id - P_WPROJ; }
    else if (id < P_W1)    { src = bproj; off = id - P_BPROJ; }
    else if (id < P_B1)    { src = w1;    off = id - P_W1; }
    else if (id < P_W2)    { src = b1;    off = id - P_B1; }
    else if (id < P_B2)    { src = w2;    off = id - P_W2; }
    else                   { src = b2;    off = id - P_B2; }
    pcan[id] = cvt(src, off, isbf);
    return;
  }
  id -= n2;
  if (id < n3) {
    mcan[id] = m8 ? (int)(((const unsigned char*)maskr)[id] != 0)
                  : (int)(((const int*)maskr)[id] != 0);
  }
}

// ---------------- K1: LN1 + QKV (wave-per-4-rows, LDS weights) ----------------
__global__ __launch_bounds__(256) void k_ln_qkv(
    const float* __restrict__ x, const float* __restrict__ pcan,
    float* __restrict__ qkv)
{
  __shared__ float wl[CH * 192];
  __shared__ float bq[192];
  const int tid = threadIdx.x;
  for (int i = tid; i < CH * 192; i += 256) wl[i] = pcan[P_WQKV + i];
  if (tid < 192) bq[tid] = pcan[P_BQKV + tid];
  __syncthreads();
  const int wave = tid >> 6, lane = tid & 63;
  const int row0 = blockIdx.x * 16 + wave * 4;
  const float gg = pcan[P_LN1G + lane], bb = pcan[P_LN1B + lane];

  float xn[4];
#pragma unroll
  for (int r = 0; r < 4; ++r) {
    float v = x[(size_t)(row0 + r) * CH + lane];
    float m = wave_sum_f32(v) * (1.0f / 64.0f);
    float d = v - m;
    float var = wave_sum_f32(d * d) * (1.0f / 64.0f);
    float rs = 1.0f / sqrtf(var + 1e-5f);
    xn[r] = d * rs * gg + bb;
  }

  const int n0 = 3 * lane;
  float a[4][3];
#pragma unroll
  for (int r = 0; r < 4; ++r) {
    a[r][0] = bq[n0]; a[r][1] = bq[n0 + 1]; a[r][2] = bq[n0 + 2];
  }
  for (int c = 0; c < CH; ++c) {
    float w0 = wl[c * 192 + n0];
    float w1 = wl[c * 192 + n0 + 1];
    float w2 = wl[c * 192 + n0 + 2];
#pragma unroll
    for (int r = 0; r < 4; ++r) {
      float s = rdlane(xn[r], c);
      a[r][0] = fmaf(s, w0, a[r][0]);
      a[r][1] = fmaf(s, w1, a[r][1]);
      a[r][2] = fmaf(s, w2, a[r][2]);
    }
  }
#pragma unroll
  for (int r = 0; r < 4; ++r) {
    size_t o = (size_t)(row0 + r) * 192 + n0;
    qkv[o] = a[r][0]; qkv[o + 1] = a[r][1]; qkv[o + 2] = a[r][2];
  }
}

// ---------------- K2: KNN — exact R5 version (known-good 58 us) ----------------
#define KROWS 4
#define CAP   128
__global__ __launch_bounds__(256) void k_knn(
    const float* __restrict__ ccan, const int* __restrict__ mcan,
    int* __restrict__ nbr)
{
  __shared__ float4 sx[NV / 4], sy[NV / 4], sz[NV / 4];   // 48 KB SoA
  __shared__ unsigned long long sbuf[KROWS][CAP];         // 4 KB
  const int tid = threadIdx.x;
  const int row0 = blockIdx.x * KROWS;
  const int b = row0 >> 12;
  const float* cb = ccan + (size_t)b * NV * 3;
  const int* mb = mcan + b * NV;

  float* fx = (float*)sx; float* fy = (float*)sy; float* fz = (float*)sz;
  for (int j = tid; j < NV; j += 256) {
    bool v = mb[j] != 0;
    float x = cb[j * 3], y = cb[j * 3 + 1], z = cb[j * 3 + 2];
    fx[j] = v ? x : 1e4f;
    fy[j] = v ? y : 1e4f;
    fz[j] = v ? z : 1e4f;
  }
  __syncthreads();
  const int wave = tid >> 6, lane = tid & 63;
  const int qi = (row0 & (NV - 1)) + wave;
  const float qx = cb[qi * 3], qy = cb[qi * 3 + 1], qz = cb[qi * 3 + 2];

  float bmin = 1e30f;
#pragma unroll 4
  for (int t = 0; t < 16; ++t) {
    float4 X = sx[lane + t * 64], Y = sy[lane + t * 64], Z = sz[lane + t * 64];
    float d0 = d2f(X.x, Y.x, Z.x, qx, qy, qz);
    float d1 = d2f(X.y, Y.y, Z.y, qx, qy, qz);
    float d2 = d2f(X.z, Y.z, Z.z, qx, qy, qz);
    float d3 = d2f(X.w, Y.w, Z.w, qx, qy, qz);
    bmin = fminf(bmin, fminf(fminf(d0, d1), fminf(d2, d3)));
  }

  const unsigned lm = __float_as_uint(bmin);
  unsigned acc = 0;
#pragma unroll 1
  for (int bit = 31; bit >= 0; --bit) {
    unsigned tr = acc | (1u << bit);
    int cnt = __popcll(__ballot(lm < tr));
    if (cnt <= KNN - 1) acc = tr;
  }
  const float T = __uint_as_float(acc + 8);

  int base = 0;
  const unsigned long long below = (lane == 0) ? 0ull : (~0ull >> (64 - lane));
#pragma unroll 4
  for (int t = 0; t < 16; ++t) {
    float4 X = sx[lane + t * 64], Y = sy[lane + t * 64], Z = sz[lane + t * 64];
    float dd[4];
    dd[0] = d2f(X.x, Y.x, Z.x, qx, qy, qz);
    dd[1] = d2f(X.y, Y.y, Z.y, qx, qy, qz);
    dd[2] = d2f(X.z, Y.z, Z.z, qx, qy, qz);
    dd[3] = d2f(X.w, Y.w, Z.w, qx, qy, qz);
#pragma unroll
    for (int e = 0; e < 4; ++e) {
      bool s = (dd[e] <= T);
      unsigned long long bal = __ballot(s);
      if (bal) {
        int pos = base + __popcll(bal & below);
        unsigned j = 4u * (unsigned)(lane + t * 64) + (unsigned)e;
        if (s && pos < CAP)
          sbuf[wave][pos] =
              ((unsigned long long)__float_as_uint(dd[e]) << 32) | j;
        base += __popcll(bal);
      }
    }
  }
  const int c = base;
  const int grow = row0 + wave;

  if (c >= KNN && c <= CAP) {
#pragma unroll
    for (int o = 0; o < 2; ++o) {
      int idx = lane + o * 64;
      if (idx < c) {
        unsigned long long mykey = sbuf[wave][idx];
        int rank = 0;
        for (int i = 0; i < c; ++i) rank += (sbuf[wave][i] < mykey);
        if (rank < KNN)
          nbr[(size_t)grow * KNN + rank] = (int)(mykey & (NV - 1));
      }
    }
  } else {
    unsigned long long arr[KNN];
#pragma unroll
    for (int t = 0; t < KNN; ++t) arr[t] = ~0ull;
    for (int t = 0; t < 16; ++t) {
      float4 X = sx[lane + t * 64], Y = sy[lane + t * 64], Z = sz[lane + t * 64];
      float dd[4];
      dd[0] = d2f(X.x, Y.x, Z.x, qx, qy, qz);
      dd[1] = d2f(X.y, Y.y, Z.y, qx, qy, qz);
      dd[2] = d2f(X.z, Y.z, Z.z, qx, qy, qz);
      dd[3] = d2f(X.w, Y.w, Z.w, qx, qy, qz);
#pragma unroll
      for (int e = 0; e < 4; ++e) {
        unsigned j = 4u * (unsigned)(lane + t * 64) + (unsigned)e;
        unsigned long long key =
            ((unsigned long long)__float_as_uint(dd[e]) << 32) | j;
        if (key < arr[KNN - 1]) {
          arr[KNN - 1] = key;
#pragma unroll
          for (int t2 = KNN - 1; t2 > 0; --t2) {
            unsigned long long a = arr[t2 - 1], cc = arr[t2];
            if (cc < a) { arr[t2 - 1] = cc; arr[t2] = a; }
          }
        }
      }
    }
    unsigned myj = 0;
#pragma unroll 1
    for (int r = 0; r < KNN; ++r) {
      unsigned hi = (unsigned)(arr[0] >> 32);
      unsigned lo = (unsigned)(arr[0] & 0xffffffffu);
      wave_min_kv(hi, lo);
      if (lane == (int)((lo >> 2) & 63u)) {
#pragma unroll
        for (int t = 0; t < KNN - 1; ++t) arr[t] = arr[t + 1];
        arr[KNN - 1] = ~0ull;
      }
      if (lane == r) myj = lo;
    }
    if (lane < KNN) nbr[(size_t)grow * KNN + lane] = (int)(myj & (NV - 1));
  }
}

// ---------------- K3: attention + proj + residual (R5 + LDS wproj) ----------------
#define AROWS 4
__global__ __launch_bounds__(256) void k_attn(
    const float* __restrict__ qkv, const int* __restrict__ nbr,
    const int* __restrict__ mcan, const float* __restrict__ xcan,
    const float* __restrict__ pcan, float* __restrict__ xres)
{
  __shared__ float wp[CH * CH];   // 16 KB wproj [c][n]
  __shared__ float bp[CH];
  __shared__ float sc[AROWS][NH][KNN];
  __shared__ float wsel[AROWS][NH][KS];
  __shared__ int   isel[AROWS][NH][KS];
  __shared__ float obuf[AROWS][CH];
  __shared__ int   nb[AROWS][KNN];
  __shared__ float npen[AROWS][KNN];
  const int tid = threadIdx.x;
  {
    const float4* src = (const float4*)(pcan + P_WPROJ);
    float4* dst = (float4*)wp;
    for (int i = tid; i < CH * CH / 4; i += 256) dst[i] = src[i];
    if (tid < CH) bp[tid] = pcan[P_BPROJ + tid];
  }
  const int wave = tid >> 6, lane = tid & 63;
  const int row = blockIdx.x * AROWS + wave;
  const int b = row / NV;

  if (lane < KNN) {
    int j = nbr[(size_t)row * KNN + lane] & (NV - 1);
    nb[wave][lane] = j;
    npen[wave][lane] = mcan[b * NV + j] ? 0.0f : -1e9f;
  }
  __syncthreads();

  if (lane < NH * KNN) {
    int h = lane / KNN, kk = lane % KNN;
    int j = nb[wave][kk];
    const float* qp = qkv + (size_t)row * 192 + h * DH;
    const float* kp = qkv + ((size_t)(b * NV + j)) * 192 + 64 + h * DH;
    float acc = 0.f;
#pragma unroll
    for (int d = 0; d < DH; ++d) acc += qp[d] * kp[d];
    sc[wave][h][kk] = acc * 0.25f + npen[wave][kk];
  }
  __syncthreads();

  if (lane < NH) {
    int h = lane;
    float sv[KS]; int sj[KS];
    unsigned used = 0;
#pragma unroll
    for (int r = 0; r < KS; ++r) {
      float best = -INFINITY; int bi = 0;
#pragma unroll
      for (int kk = 0; kk < KNN; ++kk) {
        float s = sc[wave][h][kk];
        if (!(used & (1u << kk)) && s > best) { best = s; bi = kk; }
      }
      used |= 1u << bi; sv[r] = best; sj[r] = bi;
    }
    float mx = sv[0];
    float e[KS], sum = 0.f;
#pragma unroll
    for (int r = 0; r < KS; ++r) { e[r] = expf(sv[r] - mx); sum += e[r]; }
    float inv = 1.0f / sum;
#pragma unroll
    for (int r = 0; r < KS; ++r) {
      wsel[wave][h][r] = e[r] * inv;
      isel[wave][h][r] = nb[wave][sj[r]];
    }
  }
  __syncthreads();

  {
    int h = lane >> 4, d = lane & 15;
    float o = 0.f;
#pragma unroll
    for (int r = 0; r < KS; ++r) {
      int j = isel[wave][h][r];
      o += wsel[wave][h][r] * qkv[((size_t)(b * NV + j)) * 192 + 128 + h * DH + d];
    }
    obuf[wave][lane] = o;
  }
  __syncthreads();

  {
    float acc = bp[lane];
#pragma unroll 4
    for (int cc = 0; cc < CH; ++cc)
      acc = fmaf(obuf[wave][cc], wp[cc * CH + lane], acc);
    float a = mcan[row] ? acc : 0.0f;
    xres[(size_t)row * CH + lane] = 0.5f * a + xcan[(size_t)row * CH + lane];
  }
}

// ---------------- K4: LN2 + MLP + residual (w1 LDS bf16, w2 global f32) ----------------
__global__ __launch_bounds__(256) void k_mlp(
    const float* __restrict__ xres, const float* __restrict__ pcan,
    const int* __restrict__ flags, void* __restrict__ out)
{
  __shared__ unsigned short w1b[CH * MHID];   // [c][n] 32 KB bf16
  const int tid = threadIdx.x;
  for (int i = tid; i < CH * MHID; i += 256)
    w1b[i] = __bfloat16_as_ushort(__float2bfloat16(pcan[P_W1 + i]));
  __syncthreads();
  const int wave = tid >> 6, lane = tid & 63;
  const int row0 = blockIdx.x * 16 + wave * 4;
  const float gg = pcan[P_LN2G + lane], bb = pcan[P_LN2B + lane];

  float xn[4], xv[4];
#pragma unroll
  for (int r = 0; r < 4; ++r) {
    float v = xres[(size_t)(row0 + r) * CH + lane];
    xv[r] = v;
    float m = wave_sum_f32(v) * (1.0f / 64.0f);
    float d = v - m;
    float var = wave_sum_f32(d * d) * (1.0f / 64.0f);
    float rs = 1.0f / sqrtf(var + 1e-5f);
    xn[r] = d * rs * gg + bb;
  }

  // fc1: cols n = 4*lane + i, ushort4 LDS weight reads
  const int n0 = 4 * lane;
  float g[4][4];
  {
    float4 bi = *(const float4*)(pcan + P_B1 + n0);
#pragma unroll
    for (int r = 0; r < 4; ++r) {
      g[r][0] = bi.x; g[r][1] = bi.y; g[r][2] = bi.z; g[r][3] = bi.w;
    }
  }
  for (int c = 0; c < CH; ++c) {
    ushort4 w4 = *(const ushort4*)&w1b[c * MHID + n0];
    float w0 = b2f(__ushort_as_bfloat16(w4.x));
    float w1 = b2f(__ushort_as_bfloat16(w4.y));
    float w2 = b2f(__ushort_as_bfloat16(w4.z));
    float w3 = b2f(__ushort_as_bfloat16(w4.w));
#pragma unroll
    for (int r = 0; r < 4; ++r) {
      float s = rdlane(xn[r], c);
      g[r][0] = fmaf(s, w0, g[r][0]);
      g[r][1] = fmaf(s, w1, g[r][1]);
      g[r][2] = fmaf(s, w2, g[r][2]);
      g[r][3] = fmaf(s, w3, g[r][3]);
    }
  }
  // gelu (tanh approx, fast tanh via exp)
#pragma unroll
  for (int r = 0; r < 4; ++r)
#pragma unroll
    for (int i = 0; i < 4; ++i) {
      float t = g[r][i];
      float u = 0.7978845608028654f * (t + 0.044715f * t * t * t);
      g[r][i] = 0.5f * t * (1.0f + tanh_fast(u));
    }

  // fc2: out col = lane; hidden h = hb*4 + i at lane hb, reg i.
  // w2 read from GLOBAL f32, coalesced 256B/wave per h (L2-hot).
  float acc2[4];
  {
    float bo = pcan[P_B2 + lane];
#pragma unroll
    for (int r = 0; r < 4; ++r) acc2[r] = bo;
  }
  const float* w2p = pcan + P_W2 + lane;
#pragma unroll 2
  for (int hb = 0; hb < MHID / 4; ++hb) {
#pragma unroll
    for (int i = 0; i < 4; ++i) {
      float wv = w2p[(hb * 4 + i) * CH];
#pragma unroll
      for (int r = 0; r < 4; ++r)
        acc2[r] = fmaf(rdlane(g[r][i], hb), wv, acc2[r]);
    }
  }
#pragma unroll
  for (int r = 0; r < 4; ++r) {
    float o = 0.5f * acc2[r] + xv[r];
    size_t idx = (size_t)(row0 + r) * CH + lane;
    if (flags[0]) ((bf16*)out)[idx] = __float2bfloat16(o);
    else          ((float*)out)[idx] = o;
  }
}

extern "C" void kernel_launch(void* const* d_in, const int* in_sizes, int n_in,
                              void* d_out, int out_size, void* d_ws, size_t ws_size,
                              hipStream_t stream)
{
  char* ws = (char*)d_ws;
  float* qkv  = (float*)(ws);
  float* xres = (float*)(ws + 12582912);
  float* xcan = (float*)(ws + 16777216);
  float* ccan = (float*)(ws + 20971520);
  float* pcan = (float*)(ws + 21168128);
  int*   mcan = (int*)  (ws + 21368064);
  int*   nbr  = (int*)  (ws + 21433600);
  int*   flags= (int*)  (ws + 22088960);

  k_detect<<<1, 64, 0, stream>>>((const unsigned short*)d_in[0],
                                 (const unsigned*)d_in[2], flags);
  const int total = BN * CH + NB * NV * 3 + P_TOT + BN;
  k_ingest<<<(total + 255) / 256, 256, 0, stream>>>(
      d_in[0], d_in[1], d_in[2], d_in[3], d_in[4], d_in[5], d_in[6],
      d_in[7], d_in[8], d_in[9], d_in[10], d_in[11], d_in[12], d_in[13], d_in[14],
      flags, xcan, ccan, pcan, mcan);
  k_ln_qkv<<<BN / 16, 256, 0, stream>>>(xcan, pcan, qkv);
  k_knn<<<BN / KROWS, 256, 0, stream>>>(ccan, mcan, nbr);
  k_attn<<<BN / AROWS, 256, 0, stream>>>(qkv, nbr, mcan, xcan, pcan, xres);
  k_mlp<<<BN / 16, 256, 0, stream>>>(xres, pcan, flags, d_out);
}